// Round 1
// baseline (467.137 us; speedup 1.0000x reference)
//
#include <hip/hip_runtime.h>
#include <math.h>

// ---------------------------------------------------------------------------
// HMHA: pool(4x4) -> qkv 1x1 -> per-head L2norm attention (L=256,d=32) ->
//       proj 1x1 at LOW res (commutes with upsample) -> analytic BN stats ->
//       fused bilinear-upsample + BN affine write.
// All f32 (correctness baseline; MFMA planned for later rounds).
// ---------------------------------------------------------------------------

// ---------------- pool 4x4 mean: x(16,1024,64,64) -> xr(16,1024,16,16) ------
__global__ __launch_bounds__(256) void pool_k(const float* __restrict__ x,
                                              float* __restrict__ xr) {
  long bc = blockIdx.x;                 // b*1024 + c
  int t = threadIdx.x;
  int i = t >> 4, j = t & 15;           // output pixel (i,j)
  const float* p = x + bc * 4096 + (long)i * 256 + j * 4;
  float s = 0.f;
#pragma unroll
  for (int r = 0; r < 4; ++r) {
    float4 v = *(const float4*)(p + r * 64);
    s += v.x + v.y + v.z + v.w;
  }
  xr[bc * 256 + t] = s * 0.0625f;
}

// ---------------- generic tiled f32 GEMM -----------------------------------
// C[m][n] = sum_k A[m][k] (or A[k][m] if AK) * B[k][n]
// batch: z -> (b = z>>hshift, h = z&hmask) with per-b/per-h pointer strides.
template <int BM, int BN, int BK, int TM, int TN, bool AK>
__global__ __launch_bounds__(256) void gemm_k(
    const float* __restrict__ A, const float* __restrict__ B,
    float* __restrict__ C, int K, int lda, int ldb, int ldc,
    long sAb, long sAh, long sBb, long sBh, long sCb, long sCh,
    int hmask, int hshift) {
  int z = blockIdx.z;
  int h = z & hmask;
  int b = z >> hshift;
  A += (long)b * sAb + (long)h * sAh;
  B += (long)b * sBb + (long)h * sBh;
  C += (long)b * sCb + (long)h * sCh;
  __shared__ __align__(16) float Ast[BK][BM + 4];
  __shared__ __align__(16) float Bs[BK][BN + 4];
  const int t = threadIdx.x;
  constexpr int NTN = BN / TN;
  const int tn_ = t % NTN;
  const int tm_ = t / NTN;
  const int row0 = blockIdx.y * BM;
  const int col0 = blockIdx.x * BN;
  float acc[TM][TN];
#pragma unroll
  for (int i = 0; i < TM; i++)
#pragma unroll
    for (int j = 0; j < TN; j++) acc[i][j] = 0.f;

  for (int k0 = 0; k0 < K; k0 += BK) {
    if constexpr (AK) {
      // A is K-major: A[k][m] -> direct float4 copy rows
      constexpr int TOT = BK * (BM / 4);
#pragma unroll
      for (int it = 0; it < (TOT + 255) / 256; ++it) {
        int idx = t + it * 256;
        if (idx < TOT) {
          int kk = idx / (BM / 4);
          int mq = (idx % (BM / 4)) * 4;
          float4 v = *(const float4*)&A[(long)(k0 + kk) * lda + row0 + mq];
          *(float4*)&Ast[kk][mq] = v;
        }
      }
    } else {
      // A row-major: A[m][k] -> float4 along k, transpose into LDS
      constexpr int TOT = BM * (BK / 4);
#pragma unroll
      for (int it = 0; it < (TOT + 255) / 256; ++it) {
        int idx = t + it * 256;
        if (idx < TOT) {
          int m = idx / (BK / 4);
          int kq = (idx % (BK / 4)) * 4;
          float4 v = *(const float4*)&A[(long)(row0 + m) * lda + k0 + kq];
          Ast[kq + 0][m] = v.x;
          Ast[kq + 1][m] = v.y;
          Ast[kq + 2][m] = v.z;
          Ast[kq + 3][m] = v.w;
        }
      }
    }
    {
      constexpr int TOT = BK * (BN / 4);
#pragma unroll
      for (int it = 0; it < (TOT + 255) / 256; ++it) {
        int idx = t + it * 256;
        if (idx < TOT) {
          int kk = idx / (BN / 4);
          int nq = (idx % (BN / 4)) * 4;
          float4 v = *(const float4*)&B[(long)(k0 + kk) * ldb + col0 + nq];
          *(float4*)&Bs[kk][nq] = v;
        }
      }
    }
    __syncthreads();
#pragma unroll
    for (int kk = 0; kk < BK; ++kk) {
      float av[TM], bv[TN];
#pragma unroll
      for (int i = 0; i < TM; i++) av[i] = Ast[kk][tm_ * TM + i];
#pragma unroll
      for (int j = 0; j < TN; j++) bv[j] = Bs[kk][tn_ * TN + j];
#pragma unroll
      for (int i = 0; i < TM; i++)
#pragma unroll
        for (int j = 0; j < TN; j++) acc[i][j] += av[i] * bv[j];
    }
    __syncthreads();
  }
#pragma unroll
  for (int i = 0; i < TM; i++) {
#pragma unroll
    for (int j4 = 0; j4 < TN; j4 += 4) {
      float4 v;
      v.x = acc[i][j4];
      v.y = acc[i][j4 + 1];
      v.z = acc[i][j4 + 2];
      v.w = acc[i][j4 + 3];
      *(float4*)&C[(long)(row0 + tm_ * TM + i) * ldc + col0 + tn_ * TN + j4] = v;
    }
  }
}

// ---------------- q,k L2-normalize (+temperature into q), write K-major ----
// qnT[(b*8+h)*32 + d][l], knT likewise; both 32x256 per (b,h).
__global__ __launch_bounds__(256) void norm_k(const float* __restrict__ qkv,
                                              const float* __restrict__ temp,
                                              float* __restrict__ qnT,
                                              float* __restrict__ knT) {
  int b = blockIdx.x, h = blockIdx.y, l = threadIdx.x;
  const float* qb = qkv + ((long)b * 768 + h * 32) * 256;
  const float* kb = qb + 256 * 256;
  float v[32];
  float ss = 0.f;
#pragma unroll
  for (int d = 0; d < 32; ++d) {
    v[d] = qb[d * 256 + l];
    ss += v[d] * v[d];
  }
  float sc = temp[h] / fmaxf(sqrtf(ss), 1e-12f);
  long ob = ((long)(b * 8 + h) * 32) * 256 + l;
#pragma unroll
  for (int d = 0; d < 32; ++d) qnT[ob + d * 256] = v[d] * sc;
  ss = 0.f;
#pragma unroll
  for (int d = 0; d < 32; ++d) {
    v[d] = kb[d * 256 + l];
    ss += v[d] * v[d];
  }
  sc = 1.f / fmaxf(sqrtf(ss), 1e-12f);
#pragma unroll
  for (int d = 0; d < 32; ++d) knT[ob + d * 256] = v[d] * sc;
}

// ---------------- row softmax S(z,l,:) -> transposed P^T(z,m,l) ------------
__global__ __launch_bounds__(256) void softmax_k(const float* __restrict__ S,
                                                 float* __restrict__ Pt) {
  int t = threadIdx.x, wid = t >> 6, lane = t & 63;
  long row = (long)blockIdx.x * 4 + wid;   // z*256 + l
  long z = row >> 8;
  int l = (int)(row & 255);
  const float* s = S + z * 65536 + (long)l * 256;
  float v0 = s[lane], v1 = s[lane + 64], v2 = s[lane + 128], v3 = s[lane + 192];
  float mx = fmaxf(fmaxf(v0, v1), fmaxf(v2, v3));
  for (int o = 32; o; o >>= 1) mx = fmaxf(mx, __shfl_xor(mx, o));
  float e0 = __expf(v0 - mx), e1 = __expf(v1 - mx), e2 = __expf(v2 - mx),
        e3 = __expf(v3 - mx);
  float sm = e0 + e1 + e2 + e3;
  for (int o = 32; o; o >>= 1) sm += __shfl_xor(sm, o);
  float inv = 1.f / sm;
  float* p = Pt + z * 65536 + l;
  p[(long)lane * 256] = e0 * inv;
  p[(long)(lane + 64) * 256] = e1 * inv;
  p[(long)(lane + 128) * 256] = e2 * inv;
  p[(long)(lane + 192) * 256] = e3 * inv;
}

// ---------------- analytic BN stats of bilinear-upsampled low-res field ----
// mean = sum c[i]c[j] L / 65536 ; E[x^2] via tridiagonal quadratic form A(x)A.
__global__ __launch_bounds__(256) void stats_k(const float* __restrict__ low,
                                               const float* __restrict__ gamma,
                                               const float* __restrict__ beta,
                                               float* __restrict__ kA,
                                               float* __restrict__ kB) {
  int o = blockIdx.x, t = threadIdx.x;
  __shared__ float cw[16];
  __shared__ float A3[16][3];
  __shared__ float Ls[256];
  __shared__ float r1[4], r2[4];
  if (t < 16) {
    cw[t] = 0.f;
    A3[t][0] = A3[t][1] = A3[t][2] = 0.f;
  }
  __syncthreads();
  if (t < 64) {
    float src = 0.25f * t - 0.375f;     // half-pixel mapping, scale 4
    float fl = floorf(src);
    float f = src - fl;
    int i0 = (int)fl, i1 = i0 + 1;
    i0 = max(0, min(15, i0));
    i1 = max(0, min(15, i1));
    float w0 = 1.f - f, w1 = f;
    atomicAdd(&cw[i0], w0);
    atomicAdd(&cw[i1], w1);
    if (i0 == i1)
      atomicAdd(&A3[i0][1], 1.f);       // (w0+w1)^2 = 1
    else {
      atomicAdd(&A3[i0][1], w0 * w0);
      atomicAdd(&A3[i1][1], w1 * w1);
      atomicAdd(&A3[i0][2], w0 * w1);
      atomicAdd(&A3[i1][0], w0 * w1);
    }
  }
  __syncthreads();
  int i = t >> 4, j = t & 15;
  float s1 = 0.f, s2 = 0.f;
  for (int b = 0; b < 16; ++b) {
    Ls[t] = low[((long)b * 1024 + o) * 256 + t];
    __syncthreads();
    float Lc = Ls[t];
    s1 += cw[i] * cw[j] * Lc;
    float a2 = 0.f;
#pragma unroll
    for (int di = -1; di <= 1; ++di) {
      int ii = max(0, min(15, i + di));
      float ay = A3[i][di + 1];
#pragma unroll
      for (int dj = -1; dj <= 1; ++dj) {
        int jj = max(0, min(15, j + dj));
        a2 += ay * A3[j][dj + 1] * Ls[ii * 16 + jj];
      }
    }
    s2 += a2 * Lc;
    __syncthreads();
  }
  int lane = t & 63, wid = t >> 6;
  for (int off = 32; off; off >>= 1) {
    s1 += __shfl_down(s1, off);
    s2 += __shfl_down(s2, off);
  }
  if (lane == 0) {
    r1[wid] = s1;
    r2[wid] = s2;
  }
  __syncthreads();
  if (t == 0) {
    s1 = r1[0] + r1[1] + r1[2] + r1[3];
    s2 = r2[0] + r2[1] + r2[2] + r2[3];
    float mean = s1 * (1.f / 65536.f);
    float var = s2 * (1.f / 65536.f) - mean * mean;
    float is = rsqrtf(var + 1e-5f);
    float g = gamma[o];
    kA[o] = g * is;
    kB[o] = beta[o] - mean * g * is;
  }
}

// ---------------- fused bilinear 4x upsample + BN affine, final write ------
__global__ __launch_bounds__(256) void up_bn_k(const float* __restrict__ low,
                                               const float* __restrict__ kA,
                                               const float* __restrict__ kB,
                                               float* __restrict__ out) {
  long bo = blockIdx.x;                 // b*1024 + o
  int o = (int)(bo & 1023);
  int t = threadIdx.x;
  __shared__ float Ls[256];
  Ls[t] = low[bo * 256 + t];
  __syncthreads();
  float a = kA[o], bb = kB[o];
  float* op = out + bo * 4096;
#pragma unroll
  for (int it = 0; it < 4; ++it) {
    int idx = it * 1024 + t * 4;
    int y = idx >> 6, x0 = idx & 63;
    float sy = 0.25f * y - 0.375f;
    float fly = floorf(sy);
    float fy = sy - fly;
    int y0 = max(0, min(15, (int)fly));
    int y1 = max(0, min(15, (int)fly + 1));
    const float* R0 = &Ls[y0 * 16];
    const float* R1 = &Ls[y1 * 16];
    float vout[4];
#pragma unroll
    for (int jj = 0; jj < 4; ++jj) {
      int xx = x0 + jj;
      float sx = 0.25f * xx - 0.375f;
      float flx = floorf(sx);
      float fx = sx - flx;
      int x0i = max(0, min(15, (int)flx));
      int x1i = max(0, min(15, (int)flx + 1));
      float v0 = R0[x0i] + fx * (R0[x1i] - R0[x0i]);
      float v1 = R1[x0i] + fx * (R1[x1i] - R1[x0i]);
      vout[jj] = a * (v0 + fy * (v1 - v0)) + bb;
    }
    float4 r;
    r.x = vout[0];
    r.y = vout[1];
    r.z = vout[2];
    r.w = vout[3];
    *(float4*)(op + idx) = r;
  }
}

// ---------------------------------------------------------------------------
extern "C" void kernel_launch(void* const* d_in, const int* in_sizes, int n_in,
                              void* d_out, int out_size, void* d_ws,
                              size_t ws_size, hipStream_t stream) {
  const float* x = (const float*)d_in[0];
  const float* w_qkv = (const float*)d_in[1];
  const float* temp = (const float*)d_in[2];
  const float* w_proj = (const float*)d_in[3];
  const float* gamma = (const float*)d_in[4];
  const float* beta = (const float*)d_in[5];
  float* out = (float*)d_out;
  float* ws = (float*)d_ws;

  // workspace layout (floats)
  float* xr = ws;                    // 16*1024*256     = 4,194,304
  float* qkv = xr + 4194304;         // 16*768*256      = 3,145,728
  float* qnT = qkv + 3145728;        // 128*32*256      = 1,048,576
  float* knT = qnT + 1048576;        // 1,048,576
  float* att = knT + 1048576;        // 16*256*256      = 1,048,576
  float* low = att + 1048576;        // 16*1024*256     = 4,194,304
  float* kA = low + 4194304;         // 1024
  float* kB = kA + 1024;             // 1024
  float* Sb = kB + 1024;             // 64*65536 (half batch) = 4,194,304
  float* Pt = Sb + 4194304;          // 4,194,304
  // total ~92.3 MB

  // 1) pool
  pool_k<<<16384, 256, 0, stream>>>(x, xr);

  // 2) qkv = w_qkv(768x1024) @ xr[b](1024x256)  per b
  gemm_k<128, 128, 16, 8, 8, false><<<dim3(2, 6, 16), 256, 0, stream>>>(
      w_qkv, xr, qkv, 1024, 1024, 256, 256, 0L, 0L, 262144L, 0L, 196608L, 0L,
      0, 0);

  // 3) L2 norm q (with temperature) and k, K-major outputs
  norm_k<<<dim3(16, 8), 256, 0, stream>>>(qkv, temp, qnT, knT);

  // 4) attention in two 8-batch halves to bound ws (S, P^T reuse)
  for (int half = 0; half < 2; ++half) {
    const float* qh = qnT + (long)half * 524288;
    const float* kh = knT + (long)half * 524288;
    // S[l][m] = qn^T(K-major 32x256) x kn^T : M=256,N=256,K=32
    gemm_k<64, 64, 16, 4, 4, true><<<dim3(4, 4, 64), 256, 0, stream>>>(
        qh, kh, Sb, 32, 256, 256, 256, 65536L, 8192L, 65536L, 8192L, 524288L,
        65536L, 7, 3);
    // softmax rows, write P^T
    softmax_k<<<4096, 256, 0, stream>>>(Sb, Pt);
    // out^T[d][l] = V^T(32x256 row-major, = qkv v-channels) @ P^T : M=32,N=256,K=256
    gemm_k<32, 64, 16, 2, 4, false><<<dim3(4, 1, 64), 256, 0, stream>>>(
        qkv + (long)half * 1572864 + 131072, Pt,
        att + (long)half * 524288, 256, 256, 256, 256, 196608L, 8192L,
        524288L, 65536L, 65536L, 8192L, 7, 3);
  }

  // 5) proj at LOW resolution (commutes with upsample): M=1024,N=256,K=256
  gemm_k<128, 128, 16, 8, 8, false><<<dim3(2, 8, 16), 256, 0, stream>>>(
      w_proj, att, low, 256, 256, 256, 256, 0L, 0L, 65536L, 0L, 262144L, 0L, 0,
      0);

  // 6) analytic BN stats of the (virtual) upsampled field
  stats_k<<<1024, 256, 0, stream>>>(low, gamma, beta, kA, kB);

  // 7) fused upsample + BN affine -> d_out
  up_bn_k<<<16384, 256, 0, stream>>>(low, kA, kB, out);
}

// Round 2
// 204.965 us; speedup vs baseline: 2.2791x; 2.2791x over previous
//
#include <hip/hip_runtime.h>
#include <math.h>

// ---------------------------------------------------------------------------
// HMHA round 2: all matmuls on bf16 MFMA (16x16x32), f32 accumulate.
//   pool(4x4)->xrN bf16 [n=b*256+pix][k=c]   (XCD-swizzled scatter writes)
//   qkv  = W_qkv @ xrN^T  : one MFMA GEMM M=768,N=4096,K=1024 -> bf16 [o][n]
//   norm: per-(b,h) l2norm of q (x temperature) and k -> qn,kn [bh][l][32] bf16
//   S    = qn @ kn^T (K=32, direct-global MFMA frags)  -> bf16 [bh][l][m]
//   softmax rows -> P bf16
//   O    = P @ V (K=256; V^T = rows of qkv bf16, free)  -> attN [b*256+l][td]
//   proj = W_proj @ attN^T : MFMA GEMM M=1024,N=4096,K=256 -> lowT f32 [o][n]
//   analytic BN stats of virtual upsample + fused upsample+BN write (f32).
// ---------------------------------------------------------------------------

typedef unsigned short u16;
typedef u16 u16x8 __attribute__((ext_vector_type(8)));
typedef u16 u16x4 __attribute__((ext_vector_type(4)));
typedef short s16x8 __attribute__((ext_vector_type(8)));
typedef float f32x4 __attribute__((ext_vector_type(4)));

__device__ __forceinline__ float b2f(u16 u) {
  union { unsigned u; float f; } v;
  v.u = (unsigned)u << 16;
  return v.f;
}
__device__ __forceinline__ u16 f2b(float f) {
  union { float f; unsigned u; } v;
  v.f = f;
  unsigned r = (v.u + 0x7fffu + ((v.u >> 16) & 1u)) >> 16;
  return (u16)r;
}
__device__ __forceinline__ f32x4 mfma_bf16(s16x8 a, s16x8 b, f32x4 c) {
  return __builtin_amdgcn_mfma_f32_16x16x32_bf16(a, b, c, 0, 0, 0);
}

// ---------------- f32 -> bf16 convert (weights) ----------------------------
__global__ __launch_bounds__(256) void cvt_k(const float* __restrict__ src,
                                             u16* __restrict__ dst, int n4) {
  int idx = blockIdx.x * 256 + threadIdx.x;
  if (idx < n4) {
    float4 v = ((const float4*)src)[idx];
    u16x4 o;
    o.x = f2b(v.x); o.y = f2b(v.y); o.z = f2b(v.z); o.w = f2b(v.w);
    ((u16x4*)dst)[idx] = o;
  }
}

// ---------------- pool 4x4 mean -> xrN bf16 [b*256+pix][1024] --------------
// XCD-aware swizzle: XCD x (bid&7) owns c in [x*128, x*128+128) so each 64B
// output line (32 consecutive c of one pixel row) stays within one L2.
__global__ __launch_bounds__(256) void pool_k(const float* __restrict__ x,
                                              u16* __restrict__ xrN) {
  int bid = blockIdx.x;
  int g = bid >> 3, xcd = bid & 7;
  int c = xcd * 128 + (g & 127);
  int b = g >> 7;
  int t = threadIdx.x;
  int i = t >> 4, j = t & 15;
  const float* p = x + ((long)(b * 1024 + c)) * 4096 + (long)i * 256 + j * 4;
  float s = 0.f;
#pragma unroll
  for (int r = 0; r < 4; ++r) {
    float4 v = *(const float4*)(p + r * 64);
    s += v.x + v.y + v.z + v.w;
  }
  xrN[((long)(b << 8) + t) * 1024 + c] = f2b(s * 0.0625f);
}

// ---------------- MFMA GEMM: C[M][N] = A[M][K] * B[N][K]^T -----------------
// A row-major [M][K] bf16, B N-major [N][K] bf16, C row-major (bf16 or f32).
// 128x128 block tile, BK=64, 4 waves (each 64x64 = 4x4 fragments).
template <int BK, bool OUT_BF16>
__global__ __launch_bounds__(256) void mgemm_k(const u16* __restrict__ A,
                                               const u16* __restrict__ B,
                                               void* __restrict__ C, int K,
                                               int lda, int ldb, int ldc) {
  constexpr int BM = 128, BN = 128, PAD = 8, LDT = BK + PAD;
  __shared__ u16 As[BM * LDT];
  __shared__ u16 Bs[BN * LDT];
  const int t = threadIdx.x;
  const int lane = t & 63, wave = t >> 6;
  const int l15 = lane & 15, l4 = lane >> 4;
  const int row0 = blockIdx.y * BM, col0 = blockIdx.x * BN;
  const int wr = (wave >> 1) * 64, wc = (wave & 1) * 64;
  f32x4 acc[4][4] = {};
  constexpr int CPR = BK / 8;       // 16B chunks per LDS row
  constexpr int RPP = 256 / CPR;    // rows staged per pass
  const int srow = t / CPR, sch = t % CPR;

  for (int k0 = 0; k0 < K; k0 += BK) {
    __syncthreads();
#pragma unroll
    for (int r = 0; r < BM; r += RPP) {
      u16x8 v = *(const u16x8*)&A[(long)(row0 + srow + r) * lda + k0 + sch * 8];
      *(u16x8*)&As[(srow + r) * LDT + sch * 8] = v;
    }
#pragma unroll
    for (int r = 0; r < BN; r += RPP) {
      u16x8 v = *(const u16x8*)&B[(long)(col0 + srow + r) * ldb + k0 + sch * 8];
      *(u16x8*)&Bs[(srow + r) * LDT + sch * 8] = v;
    }
    __syncthreads();
#pragma unroll
    for (int kk = 0; kk < BK / 32; ++kk) {
      s16x8 a[4], bfr[4];
#pragma unroll
      for (int i = 0; i < 4; i++)
        a[i] = *(const s16x8*)&As[(wr + i * 16 + l15) * LDT + kk * 32 + l4 * 8];
#pragma unroll
      for (int j = 0; j < 4; j++)
        bfr[j] = *(const s16x8*)&Bs[(wc + j * 16 + l15) * LDT + kk * 32 + l4 * 8];
#pragma unroll
      for (int i = 0; i < 4; i++)
#pragma unroll
        for (int j = 0; j < 4; j++)
          acc[i][j] = mfma_bf16(a[i], bfr[j], acc[i][j]);
    }
  }
#pragma unroll
  for (int i = 0; i < 4; i++)
#pragma unroll
    for (int j = 0; j < 4; j++)
#pragma unroll
      for (int q = 0; q < 4; q++) {
        long r = row0 + wr + i * 16 + l4 * 4 + q;
        long c = col0 + wc + j * 16 + l15;
        if constexpr (OUT_BF16)
          ((u16*)C)[r * ldc + c] = f2b(acc[i][j][q]);
        else
          ((float*)C)[r * ldc + c] = acc[i][j][q];
      }
}

// ---------------- q,k l2-normalize (temp folded into q) --------------------
// qkv bf16 [768][4096]; out qn,kn bf16 [bh][l][32]
__global__ __launch_bounds__(256) void norm_k(const u16* __restrict__ qkv,
                                              const float* __restrict__ temp,
                                              u16* __restrict__ qn,
                                              u16* __restrict__ kn) {
  int b = blockIdx.x, h = blockIdx.y, l = threadIdx.x;
  long bq = (long)(h * 32) * 4096 + b * 256 + l;
  long bk = (long)(256 + h * 32) * 4096 + b * 256 + l;
  long ob = ((long)(b * 8 + h) * 256 + l) * 32;
  float v[32], ss = 0.f;
#pragma unroll
  for (int d = 0; d < 32; ++d) {
    v[d] = b2f(qkv[bq + (long)d * 4096]);
    ss += v[d] * v[d];
  }
  float sc = temp[h] / fmaxf(sqrtf(ss), 1e-12f);
  u16 tmp[32];
#pragma unroll
  for (int d = 0; d < 32; ++d) tmp[d] = f2b(v[d] * sc);
#pragma unroll
  for (int q8 = 0; q8 < 4; ++q8)
    *(u16x8*)&qn[ob + q8 * 8] = *(const u16x8*)&tmp[q8 * 8];
  ss = 0.f;
#pragma unroll
  for (int d = 0; d < 32; ++d) {
    v[d] = b2f(qkv[bk + (long)d * 4096]);
    ss += v[d] * v[d];
  }
  sc = 1.f / fmaxf(sqrtf(ss), 1e-12f);
#pragma unroll
  for (int d = 0; d < 32; ++d) tmp[d] = f2b(v[d] * sc);
#pragma unroll
  for (int q8 = 0; q8 < 4; ++q8)
    *(u16x8*)&kn[ob + q8 * 8] = *(const u16x8*)&tmp[q8 * 8];
}

// ---------------- S = qn @ kn^T (K=32, one MFMA step, no LDS) --------------
__global__ __launch_bounds__(256) void sgemm_k(const u16* __restrict__ qn,
                                               const u16* __restrict__ kn,
                                               u16* __restrict__ S) {
  int bh = blockIdx.z;
  int t = threadIdx.x, lane = t & 63, wave = t >> 6;
  int l15 = lane & 15, l4 = lane >> 4;
  int r0 = blockIdx.y * 128 + (wave >> 1) * 64;
  int c0 = blockIdx.x * 128 + (wave & 1) * 64;
  const u16* q = qn + (long)bh * 8192;
  const u16* k = kn + (long)bh * 8192;
  s16x8 a[4], bfr[4];
#pragma unroll
  for (int i = 0; i < 4; i++)
    a[i] = *(const s16x8*)&q[(r0 + i * 16 + l15) * 32 + l4 * 8];
#pragma unroll
  for (int j = 0; j < 4; j++)
    bfr[j] = *(const s16x8*)&k[(c0 + j * 16 + l15) * 32 + l4 * 8];
  f32x4 acc[4][4] = {};
#pragma unroll
  for (int i = 0; i < 4; i++)
#pragma unroll
    for (int j = 0; j < 4; j++)
      acc[i][j] = mfma_bf16(a[i], bfr[j], acc[i][j]);
  u16* s = S + (long)bh * 65536;
#pragma unroll
  for (int i = 0; i < 4; i++)
#pragma unroll
    for (int j = 0; j < 4; j++)
#pragma unroll
      for (int qq = 0; qq < 4; qq++)
        s[(long)(r0 + i * 16 + l4 * 4 + qq) * 256 + c0 + j * 16 + l15] =
            f2b(acc[i][j][qq]);
}

// ---------------- row softmax: S bf16 -> P bf16 ----------------------------
__global__ __launch_bounds__(256) void softmax_k(const u16* __restrict__ S,
                                                 u16* __restrict__ P) {
  int t = threadIdx.x, wid = t >> 6, lane = t & 63;
  long row = (long)blockIdx.x * 4 + wid;
  const u16* s = S + row * 256 + lane * 4;
  float v[4];
#pragma unroll
  for (int q = 0; q < 4; ++q) v[q] = b2f(s[q]);
  float mx = fmaxf(fmaxf(v[0], v[1]), fmaxf(v[2], v[3]));
  for (int o = 32; o; o >>= 1) mx = fmaxf(mx, __shfl_xor(mx, o));
  float e[4], sm = 0.f;
#pragma unroll
  for (int q = 0; q < 4; ++q) {
    e[q] = __expf(v[q] - mx);
    sm += e[q];
  }
  for (int o = 32; o; o >>= 1) sm += __shfl_xor(sm, o);
  float inv = 1.f / sm;
  u16x4 o4;
  o4.x = f2b(e[0] * inv); o4.y = f2b(e[1] * inv);
  o4.z = f2b(e[2] * inv); o4.w = f2b(e[3] * inv);
  *(u16x4*)(P + row * 256 + lane * 4) = o4;
}

// ---------------- O = P @ V  (K=256; V^T = qkv rows, direct-global) --------
// out attN bf16 [b*256+l][256]  (cols td = h*32+d)
__global__ __launch_bounds__(256) void pv_k(const u16* __restrict__ P,
                                            const u16* __restrict__ qkv,
                                            u16* __restrict__ attN) {
  int bh = blockIdx.z, b = bh >> 3, h = bh & 7;
  int t = threadIdx.x, lane = t & 63, wave = t >> 6;
  int l15 = lane & 15, l4 = lane >> 4;
  int r0 = blockIdx.x * 128 + wave * 32;
  const u16* Pp = P + (long)bh * 65536;
  const u16* V = qkv + (long)(512 + h * 32) * 4096 + b * 256;
  f32x4 acc[2][2] = {};
  for (int m0 = 0; m0 < 256; m0 += 32) {
    s16x8 a[2], bfr[2];
#pragma unroll
    for (int i = 0; i < 2; i++)
      a[i] = *(const s16x8*)&Pp[(long)(r0 + i * 16 + l15) * 256 + m0 + l4 * 8];
#pragma unroll
    for (int j = 0; j < 2; j++)
      bfr[j] = *(const s16x8*)&V[(long)(j * 16 + l15) * 4096 + m0 + l4 * 8];
#pragma unroll
    for (int i = 0; i < 2; i++)
#pragma unroll
      for (int j = 0; j < 2; j++)
        acc[i][j] = mfma_bf16(a[i], bfr[j], acc[i][j]);
  }
#pragma unroll
  for (int i = 0; i < 2; i++)
#pragma unroll
    for (int j = 0; j < 2; j++)
#pragma unroll
      for (int q = 0; q < 4; q++)
        attN[(long)(b * 256 + r0 + i * 16 + l4 * 4 + q) * 256 + h * 32 +
             j * 16 + l15] = f2b(acc[i][j][q]);
}

// ---------------- analytic BN stats (lowT f32 [1024][4096]) ----------------
__global__ __launch_bounds__(256) void stats_k(const float* __restrict__ low,
                                               const float* __restrict__ gamma,
                                               const float* __restrict__ beta,
                                               float* __restrict__ kA,
                                               float* __restrict__ kB) {
  int o = blockIdx.x, t = threadIdx.x;
  __shared__ float cw[16];
  __shared__ float A3[16][3];
  __shared__ float Ls[256];
  __shared__ float r1[4], r2[4];
  if (t < 16) {
    cw[t] = 0.f;
    A3[t][0] = A3[t][1] = A3[t][2] = 0.f;
  }
  __syncthreads();
  if (t < 64) {
    float src = 0.25f * t - 0.375f;
    float fl = floorf(src);
    float f = src - fl;
    int i0 = (int)fl, i1 = i0 + 1;
    i0 = max(0, min(15, i0));
    i1 = max(0, min(15, i1));
    float w0 = 1.f - f, w1 = f;
    atomicAdd(&cw[i0], w0);
    atomicAdd(&cw[i1], w1);
    if (i0 == i1)
      atomicAdd(&A3[i0][1], 1.f);
    else {
      atomicAdd(&A3[i0][1], w0 * w0);
      atomicAdd(&A3[i1][1], w1 * w1);
      atomicAdd(&A3[i0][2], w0 * w1);
      atomicAdd(&A3[i1][0], w0 * w1);
    }
  }
  __syncthreads();
  int i = t >> 4, j = t & 15;
  float s1 = 0.f, s2 = 0.f;
  for (int b = 0; b < 16; ++b) {
    Ls[t] = low[(long)o * 4096 + b * 256 + t];
    __syncthreads();
    float Lc = Ls[t];
    s1 += cw[i] * cw[j] * Lc;
    float a2 = 0.f;
#pragma unroll
    for (int di = -1; di <= 1; ++di) {
      int ii = max(0, min(15, i + di));
      float ay = A3[i][di + 1];
#pragma unroll
      for (int dj = -1; dj <= 1; ++dj) {
        int jj = max(0, min(15, j + dj));
        a2 += ay * A3[j][dj + 1] * Ls[ii * 16 + jj];
      }
    }
    s2 += a2 * Lc;
    __syncthreads();
  }
  int lane = t & 63, wid = t >> 6;
  for (int off = 32; off; off >>= 1) {
    s1 += __shfl_down(s1, off);
    s2 += __shfl_down(s2, off);
  }
  if (lane == 0) {
    r1[wid] = s1;
    r2[wid] = s2;
  }
  __syncthreads();
  if (t == 0) {
    s1 = r1[0] + r1[1] + r1[2] + r1[3];
    s2 = r2[0] + r2[1] + r2[2] + r2[3];
    float mean = s1 * (1.f / 65536.f);
    float var = s2 * (1.f / 65536.f) - mean * mean;
    float is = rsqrtf(var + 1e-5f);
    float g = gamma[o];
    kA[o] = g * is;
    kB[o] = beta[o] - mean * g * is;
  }
}

// ---------------- fused bilinear 4x upsample + BN affine -------------------
__global__ __launch_bounds__(256) void up_bn_k(const float* __restrict__ low,
                                               const float* __restrict__ kA,
                                               const float* __restrict__ kB,
                                               float* __restrict__ out) {
  long bo = blockIdx.x;               // b*1024 + o
  int b = (int)(bo >> 10), o = (int)(bo & 1023);
  int t = threadIdx.x;
  __shared__ float Ls[256];
  Ls[t] = low[(long)o * 4096 + b * 256 + t];
  __syncthreads();
  float a = kA[o], bb = kB[o];
  float* op = out + bo * 4096;
#pragma unroll
  for (int it = 0; it < 4; ++it) {
    int idx = it * 1024 + t * 4;
    int y = idx >> 6, x0 = idx & 63;
    float sy = 0.25f * y - 0.375f;
    float fly = floorf(sy);
    float fy = sy - fly;
    int y0 = max(0, min(15, (int)fly));
    int y1 = max(0, min(15, (int)fly + 1));
    const float* R0 = &Ls[y0 * 16];
    const float* R1 = &Ls[y1 * 16];
    float vout[4];
#pragma unroll
    for (int jj = 0; jj < 4; ++jj) {
      int xx = x0 + jj;
      float sx = 0.25f * xx - 0.375f;
      float flx = floorf(sx);
      float fx = sx - flx;
      int x0i = max(0, min(15, (int)flx));
      int x1i = max(0, min(15, (int)flx + 1));
      float v0 = R0[x0i] + fx * (R0[x1i] - R0[x0i]);
      float v1 = R1[x0i] + fx * (R1[x1i] - R1[x0i]);
      vout[jj] = a * (v0 + fy * (v1 - v0)) + bb;
    }
    float4 r;
    r.x = vout[0]; r.y = vout[1]; r.z = vout[2]; r.w = vout[3];
    *(float4*)(op + idx) = r;
  }
}

// ---------------------------------------------------------------------------
extern "C" void kernel_launch(void* const* d_in, const int* in_sizes, int n_in,
                              void* d_out, int out_size, void* d_ws,
                              size_t ws_size, hipStream_t stream) {
  const float* x = (const float*)d_in[0];
  const float* w_qkv = (const float*)d_in[1];
  const float* temp = (const float*)d_in[2];
  const float* w_proj = (const float*)d_in[3];
  const float* gamma = (const float*)d_in[4];
  const float* beta = (const float*)d_in[5];
  float* out = (float*)d_out;
  char* w = (char*)d_ws;

  u16* wqkv_b = (u16*)(w);                    // 768*1024*2      = 1.50 MB
  u16* wproj_b = (u16*)(w + 1572864);         // 1024*256*2      = 0.50 MB
  u16* xrN = (u16*)(w + 2097152);             // 4096*1024*2     = 8.0 MB
  u16* qkvb = (u16*)(w + 10485760);           // 768*4096*2      = 6.0 MB
  u16* qn = (u16*)(w + 16777216);             // 128*256*32*2    = 2.0 MB
  u16* kn = (u16*)(w + 18874368);             // 2.0 MB
  u16* S = (u16*)(w + 20971520);              // 128*256*256*2   = 16 MB
  u16* P = (u16*)(w + 37748736);              // 16 MB
  u16* attN = (u16*)(w + 54525952);           // 4096*256*2      = 2.0 MB
  float* lowT = (float*)(w + 56623104);       // 1024*4096*4     = 16 MB
  float* kA = (float*)(w + 73400320);
  float* kB = (float*)(w + 73404416);
  // total ~73.4 MB

  // 1) weight conversion to bf16
  cvt_k<<<768, 256, 0, stream>>>(w_qkv, wqkv_b, 196608);
  cvt_k<<<256, 256, 0, stream>>>(w_proj, wproj_b, 65536);

  // 2) pool -> xrN bf16 [n][k]
  pool_k<<<16384, 256, 0, stream>>>(x, xrN);

  // 3) qkv GEMM: M=768, N=4096, K=1024 -> qkvb bf16 [768][4096]
  mgemm_k<64, true><<<dim3(32, 6), 256, 0, stream>>>(wqkv_b, xrN, qkvb, 1024,
                                                     1024, 1024, 4096);

  // 4) l2 norm (temperature folded into q)
  norm_k<<<dim3(16, 8), 256, 0, stream>>>(qkvb, temp, qn, kn);

  // 5) scores S = qn kn^T
  sgemm_k<<<dim3(2, 2, 128), 256, 0, stream>>>(qn, kn, S);

  // 6) softmax
  softmax_k<<<8192, 256, 0, stream>>>(S, P);

  // 7) O = P V -> attN [b*256+l][256]
  pv_k<<<dim3(2, 1, 128), 256, 0, stream>>>(P, qkvb, attN);

  // 8) proj GEMM at low res: M=1024, N=4096, K=256 -> lowT f32 [1024][4096]
  mgemm_k<64, false><<<dim3(32, 8), 256, 0, stream>>>(wproj_b, attN, lowT, 256,
                                                      256, 256, 4096);

  // 9) analytic BN stats
  stats_k<<<1024, 256, 0, stream>>>(lowT, gamma, beta, kA, kB);

  // 10) fused upsample + BN -> out
  up_bn_k<<<16384, 256, 0, stream>>>(lowT, kA, kB, out);
}

// Round 3
// 185.867 us; speedup vs baseline: 2.5133x; 1.1028x over previous
//
#include <hip/hip_runtime.h>
#include <math.h>

// ---------------------------------------------------------------------------
// HMHA round 3:
//   - mgemm: global_load_lds(16B) staging, linear LDS + XOR-chunk swizzle
//     (involution on both source addr and ds_read addr).
//   - attn_k: ONE fused kernel = l2norm(q,k) + QK^T + online softmax + PV.
//   - cvt2: both weight conversions in one launch.
//   - pool / proj / analytic-BN stats / fused upsample+BN unchanged.
// ---------------------------------------------------------------------------

typedef unsigned short u16;
typedef u16 u16x8 __attribute__((ext_vector_type(8)));
typedef u16 u16x4 __attribute__((ext_vector_type(4)));
typedef short s16x8 __attribute__((ext_vector_type(8)));
typedef float f32x4 __attribute__((ext_vector_type(4)));

__device__ __forceinline__ float b2f(u16 u) {
  union { unsigned u; float f; } v;
  v.u = (unsigned)u << 16;
  return v.f;
}
__device__ __forceinline__ u16 f2b(float f) {
  union { float f; unsigned u; } v;
  v.f = f;
  unsigned r = (v.u + 0x7fffu + ((v.u >> 16) & 1u)) >> 16;
  return (u16)r;
}
__device__ __forceinline__ f32x4 mfma_bf16(s16x8 a, s16x8 b, f32x4 c) {
  return __builtin_amdgcn_mfma_f32_16x16x32_bf16(a, b, c, 0, 0, 0);
}
// global -> LDS direct 16B load (dest = wave-uniform base + lane*16)
__device__ __forceinline__ void gload16(const u16* g, u16* l) {
  unsigned loff = (unsigned)(unsigned long long)l;  // LDS aperture: low32 = offset
  __builtin_amdgcn_global_load_lds(
      (const __attribute__((address_space(1))) void*)g,
      (__attribute__((address_space(3))) void*)loff, 16, 0, 0);
}

// ---------------- both weight conversions, one launch -----------------------
__global__ __launch_bounds__(256) void cvt2_k(const float* __restrict__ a,
                                              u16* __restrict__ da, int n4a,
                                              const float* __restrict__ b,
                                              u16* __restrict__ db, int n4b) {
  int idx = blockIdx.x * 256 + threadIdx.x;
  const float* s;
  u16* d;
  if (idx < n4a) {
    s = a; d = da;
  } else {
    idx -= n4a;
    if (idx >= n4b) return;
    s = b; d = db;
  }
  float4 v = ((const float4*)s)[idx];
  u16x4 o;
  o.x = f2b(v.x); o.y = f2b(v.y); o.z = f2b(v.z); o.w = f2b(v.w);
  ((u16x4*)d)[idx] = o;
}

// ---------------- pool 4x4 mean -> xrN bf16 [b*256+pix][1024] ---------------
__global__ __launch_bounds__(256) void pool_k(const float* __restrict__ x,
                                              u16* __restrict__ xrN) {
  int bid = blockIdx.x;
  int g = bid >> 3, xcd = bid & 7;
  int c = xcd * 128 + (g & 127);
  int b = g >> 7;
  int t = threadIdx.x;
  int i = t >> 4, j = t & 15;
  const float* p = x + ((long)(b * 1024 + c)) * 4096 + (long)i * 256 + j * 4;
  float s = 0.f;
#pragma unroll
  for (int r = 0; r < 4; ++r) {
    float4 v = *(const float4*)(p + r * 64);
    s += v.x + v.y + v.z + v.w;
  }
  xrN[((long)(b << 8) + t) * 1024 + c] = f2b(s * 0.0625f);
}

// ---------------- MFMA GEMM, global_load_lds + XOR swizzle ------------------
// C[M][N] = A[M][K] * B[N][K]^T. 128x128 tile, BK=64, 4 waves of 64x64.
// LDS linear [128 rows][64 k]; chunk(16B) swizzle: phys = logical ^ (row&7),
// applied identically on the global source address and the ds_read address.
template <bool OUT_BF16>
__global__ __launch_bounds__(256) void mgemm_k(const u16* __restrict__ A,
                                               const u16* __restrict__ B,
                                               void* __restrict__ C, int K,
                                               int lda, int ldb, int ldc) {
  constexpr int BM = 128, BN = 128, BK = 64;
  __shared__ u16 As[BM * BK];
  __shared__ u16 Bs[BN * BK];
  const int t = threadIdx.x;
  const int lane = t & 63, wave = t >> 6;
  const int l15 = lane & 15, l4 = lane >> 4;
  const int row0 = blockIdx.y * BM, col0 = blockIdx.x * BN;
  const int wr = (wave >> 1) * 64, wc = (wave & 1) * 64;
  const int srow = t >> 3;               // staging row for this thread
  const int sch = (t & 7) ^ (srow & 7);  // swizzled source chunk
  f32x4 acc[4][4] = {};

  for (int k0 = 0; k0 < K; k0 += BK) {
    __syncthreads();
#pragma unroll
    for (int p = 0; p < 4; ++p) {   // 4 passes x 256 thr x 16B = 16 KB
      gload16(&A[(long)(row0 + p * 32 + srow) * lda + k0 + sch * 8],
              &As[(p * 256 + wave * 64) * 8]);
      gload16(&B[(long)(col0 + p * 32 + srow) * ldb + k0 + sch * 8],
              &Bs[(p * 256 + wave * 64) * 8]);
    }
    __syncthreads();
#pragma unroll
    for (int kk = 0; kk < BK / 32; ++kk) {
      s16x8 a[4], bfr[4];
#pragma unroll
      for (int i = 0; i < 4; i++) {
        int r = wr + i * 16 + l15;
        int ph = (kk * 4 + l4) ^ (r & 7);
        a[i] = *(const s16x8*)&As[r * 64 + ph * 8];
      }
#pragma unroll
      for (int j = 0; j < 4; j++) {
        int r = wc + j * 16 + l15;
        int ph = (kk * 4 + l4) ^ (r & 7);
        bfr[j] = *(const s16x8*)&Bs[r * 64 + ph * 8];
      }
#pragma unroll
      for (int i = 0; i < 4; i++)
#pragma unroll
        for (int j = 0; j < 4; j++)
          acc[i][j] = mfma_bf16(a[i], bfr[j], acc[i][j]);
    }
  }
#pragma unroll
  for (int i = 0; i < 4; i++)
#pragma unroll
    for (int j = 0; j < 4; j++)
#pragma unroll
      for (int q = 0; q < 4; q++) {
        long r = row0 + wr + i * 16 + l4 * 4 + q;
        long c = col0 + wc + j * 16 + l15;
        if constexpr (OUT_BF16)
          ((u16*)C)[r * ldc + c] = f2b(acc[i][j][q]);
        else
          ((float*)C)[r * ldc + c] = acc[i][j][q];
      }
}

// ---------------- fused attention: norm + QK^T + softmax + PV ---------------
// grid 256: block = (bh, half). 4 waves x 32 q-rows. K/V full per block.
__global__ __launch_bounds__(256) void attn_k(const u16* __restrict__ qkv,
                                              const float* __restrict__ temp,
                                              u16* __restrict__ attN) {
  int blk = blockIdx.x;
  int bh = blk >> 1, half = blk & 1;
  int b = bh >> 3, h = bh & 7;
  __shared__ u16 qs[128][40];   // q rows (this half), l2-normed * temp
  __shared__ u16 ks[256][40];   // key rows, l2-normed
  __shared__ u16 vs[32][264];   // V^T [d][m]
  __shared__ u16 Ps[4][32][40]; // per-wave P chunk transpose buffer
  int t = threadIdx.x, lane = t & 63, wave = t >> 6;
  int l15 = lane & 15, l4 = lane >> 4;
  long base = (long)b * 256;

  {  // stage V^T rows (contiguous in qkv)
    const u16* V = qkv + (long)(512 + h * 32) * 4096 + base;
#pragma unroll
    for (int p = 0; p < 4; ++p) {
      int c = p * 256 + t;
      int row = c >> 5, off = (c & 31) * 8;
      *(u16x8*)&vs[row][off] = *(const u16x8*)&V[(long)row * 4096 + off];
    }
  }
  {  // stage K with l2norm: thread t owns key l=t
    const u16* Kp = qkv + (long)(256 + h * 32) * 4096 + base + t;
    float v[32], ss = 0.f;
#pragma unroll
    for (int d = 0; d < 32; ++d) {
      v[d] = b2f(Kp[(long)d * 4096]);
      ss += v[d] * v[d];
    }
    float sc = 1.f / fmaxf(sqrtf(ss), 1e-12f);
#pragma unroll
    for (int d = 0; d < 32; ++d) ks[t][d] = f2b(v[d] * sc);
  }
  if (t < 128) {  // stage this half's Q with l2norm * temperature
    const u16* Qp = qkv + (long)(h * 32) * 4096 + base + half * 128 + t;
    float v[32], ss = 0.f;
#pragma unroll
    for (int d = 0; d < 32; ++d) {
      v[d] = b2f(Qp[(long)d * 4096]);
      ss += v[d] * v[d];
    }
    float sc = temp[h] / fmaxf(sqrtf(ss), 1e-12f);
#pragma unroll
    for (int d = 0; d < 32; ++d) qs[t][d] = f2b(v[d] * sc);
  }
  __syncthreads();

  int r0 = wave * 32;
  s16x8 aq[2];
#pragma unroll
  for (int i = 0; i < 2; ++i)
    aq[i] = *(const s16x8*)&qs[r0 + i * 16 + l15][l4 * 8];
  f32x4 O[2][2] = {};
  float mrow[2][4], lrow[2][4];
#pragma unroll
  for (int i = 0; i < 2; ++i)
#pragma unroll
    for (int q = 0; q < 4; ++q) {
      mrow[i][q] = -1e30f;
      lrow[i][q] = 0.f;
    }

  for (int m0 = 0; m0 < 256; m0 += 32) {
    // S chunk = q(32 rows) . k(32 keys)^T, K=32(d): one MFMA step
    f32x4 s[2][2] = {};
    s16x8 bk_[2];
#pragma unroll
    for (int j = 0; j < 2; ++j)
      bk_[j] = *(const s16x8*)&ks[m0 + j * 16 + l15][l4 * 8];
#pragma unroll
    for (int i = 0; i < 2; ++i)
#pragma unroll
      for (int j = 0; j < 2; ++j)
        s[i][j] = mfma_bf16(aq[i], bk_[j], s[i][j]);
    // online softmax per row (i,q); row cols live in l15 x j
#pragma unroll
    for (int i = 0; i < 2; ++i) {
      float cm[4];
#pragma unroll
      for (int q = 0; q < 4; ++q) cm[q] = fmaxf(s[i][0][q], s[i][1][q]);
#pragma unroll
      for (int sh = 1; sh < 16; sh <<= 1)
#pragma unroll
        for (int q = 0; q < 4; ++q) cm[q] = fmaxf(cm[q], __shfl_xor(cm[q], sh));
      float al[4], ps[4];
#pragma unroll
      for (int q = 0; q < 4; ++q) {
        float mn = fmaxf(mrow[i][q], cm[q]);
        al[q] = __expf(mrow[i][q] - mn);
        mrow[i][q] = mn;
        float p0 = __expf(s[i][0][q] - mn);
        float p1 = __expf(s[i][1][q] - mn);
        s[i][0][q] = p0;
        s[i][1][q] = p1;
        ps[q] = p0 + p1;
      }
#pragma unroll
      for (int sh = 1; sh < 16; sh <<= 1)
#pragma unroll
        for (int q = 0; q < 4; ++q) ps[q] += __shfl_xor(ps[q], sh);
#pragma unroll
      for (int q = 0; q < 4; ++q) lrow[i][q] = lrow[i][q] * al[q] + ps[q];
#pragma unroll
      for (int jd = 0; jd < 2; ++jd)
#pragma unroll
        for (int q = 0; q < 4; ++q) O[i][jd][q] *= al[q];
      // transpose P chunk into LDS (C-layout -> A-fragment layout)
#pragma unroll
      for (int j = 0; j < 2; ++j)
#pragma unroll
        for (int q = 0; q < 4; ++q)
          Ps[wave][i * 16 + l4 * 4 + q][j * 16 + l15] = f2b(s[i][j][q]);
    }
    // PV: O += P(32q x 32m) . V(32m x 32d)
    s16x8 pa[2], bv[2];
#pragma unroll
    for (int i = 0; i < 2; ++i)
      pa[i] = *(const s16x8*)&Ps[wave][i * 16 + l15][l4 * 8];
#pragma unroll
    for (int jd = 0; jd < 2; ++jd)
      bv[jd] = *(const s16x8*)&vs[jd * 16 + l15][m0 + l4 * 8];
#pragma unroll
    for (int i = 0; i < 2; ++i)
#pragma unroll
      for (int jd = 0; jd < 2; ++jd)
        O[i][jd] = mfma_bf16(pa[i], bv[jd], O[i][jd]);
  }
  // epilogue: 1/l scale, write attN [b*256+l][h*32+d]
  long rbase = base + half * 128 + r0;
#pragma unroll
  for (int i = 0; i < 2; ++i)
#pragma unroll
    for (int jd = 0; jd < 2; ++jd)
#pragma unroll
      for (int q = 0; q < 4; ++q)
        attN[(rbase + i * 16 + l4 * 4 + q) * 256 + h * 32 + jd * 16 + l15] =
            f2b(O[i][jd][q] / lrow[i][q]);
}

// ---------------- analytic BN stats (lowT f32 [1024][4096]) -----------------
__global__ __launch_bounds__(256) void stats_k(const float* __restrict__ low,
                                               const float* __restrict__ gamma,
                                               const float* __restrict__ beta,
                                               float* __restrict__ kA,
                                               float* __restrict__ kB) {
  int o = blockIdx.x, t = threadIdx.x;
  __shared__ float cw[16];
  __shared__ float A3[16][3];
  __shared__ float Ls[256];
  __shared__ float r1[4], r2[4];
  if (t < 16) {
    cw[t] = 0.f;
    A3[t][0] = A3[t][1] = A3[t][2] = 0.f;
  }
  __syncthreads();
  if (t < 64) {
    float src = 0.25f * t - 0.375f;
    float fl = floorf(src);
    float f = src - fl;
    int i0 = (int)fl, i1 = i0 + 1;
    i0 = max(0, min(15, i0));
    i1 = max(0, min(15, i1));
    float w0 = 1.f - f, w1 = f;
    atomicAdd(&cw[i0], w0);
    atomicAdd(&cw[i1], w1);
    if (i0 == i1)
      atomicAdd(&A3[i0][1], 1.f);
    else {
      atomicAdd(&A3[i0][1], w0 * w0);
      atomicAdd(&A3[i1][1], w1 * w1);
      atomicAdd(&A3[i0][2], w0 * w1);
      atomicAdd(&A3[i1][0], w0 * w1);
    }
  }
  __syncthreads();
  int i = t >> 4, j = t & 15;
  float s1 = 0.f, s2 = 0.f;
  for (int b = 0; b < 16; ++b) {
    Ls[t] = low[(long)o * 4096 + b * 256 + t];
    __syncthreads();
    float Lc = Ls[t];
    s1 += cw[i] * cw[j] * Lc;
    float a2 = 0.f;
#pragma unroll
    for (int di = -1; di <= 1; ++di) {
      int ii = max(0, min(15, i + di));
      float ay = A3[i][di + 1];
#pragma unroll
      for (int dj = -1; dj <= 1; ++dj) {
        int jj = max(0, min(15, j + dj));
        a2 += ay * A3[j][dj + 1] * Ls[ii * 16 + jj];
      }
    }
    s2 += a2 * Lc;
    __syncthreads();
  }
  int lane = t & 63, wid = t >> 6;
  for (int off = 32; off; off >>= 1) {
    s1 += __shfl_down(s1, off);
    s2 += __shfl_down(s2, off);
  }
  if (lane == 0) {
    r1[wid] = s1;
    r2[wid] = s2;
  }
  __syncthreads();
  if (t == 0) {
    s1 = r1[0] + r1[1] + r1[2] + r1[3];
    s2 = r2[0] + r2[1] + r2[2] + r2[3];
    float mean = s1 * (1.f / 65536.f);
    float var = s2 * (1.f / 65536.f) - mean * mean;
    float is = rsqrtf(var + 1e-5f);
    float g = gamma[o];
    kA[o] = g * is;
    kB[o] = beta[o] - mean * g * is;
  }
}

// ---------------- fused bilinear 4x upsample + BN affine --------------------
__global__ __launch_bounds__(256) void up_bn_k(const float* __restrict__ low,
                                               const float* __restrict__ kA,
                                               const float* __restrict__ kB,
                                               float* __restrict__ out) {
  long bo = blockIdx.x;               // b*1024 + o
  int b = (int)(bo >> 10), o = (int)(bo & 1023);
  int t = threadIdx.x;
  __shared__ float Ls[256];
  Ls[t] = low[(long)o * 4096 + b * 256 + t];
  __syncthreads();
  float a = kA[o], bb = kB[o];
  float* op = out + bo * 4096;
#pragma unroll
  for (int it = 0; it < 4; ++it) {
    int idx = it * 1024 + t * 4;
    int y = idx >> 6, x0 = idx & 63;
    float sy = 0.25f * y - 0.375f;
    float fly = floorf(sy);
    float fy = sy - fly;
    int y0 = max(0, min(15, (int)fly));
    int y1 = max(0, min(15, (int)fly + 1));
    const float* R0 = &Ls[y0 * 16];
    const float* R1 = &Ls[y1 * 16];
    float vout[4];
#pragma unroll
    for (int jj = 0; jj < 4; ++jj) {
      int xx = x0 + jj;
      float sx = 0.25f * xx - 0.375f;
      float flx = floorf(sx);
      float fx = sx - flx;
      int x0i = max(0, min(15, (int)flx));
      int x1i = max(0, min(15, (int)flx + 1));
      float v0 = R0[x0i] + fx * (R0[x1i] - R0[x0i]);
      float v1 = R1[x0i] + fx * (R1[x1i] - R1[x0i]);
      vout[jj] = a * (v0 + fy * (v1 - v0)) + bb;
    }
    float4 r;
    r.x = vout[0]; r.y = vout[1]; r.z = vout[2]; r.w = vout[3];
    *(float4*)(op + idx) = r;
  }
}

// ---------------------------------------------------------------------------
extern "C" void kernel_launch(void* const* d_in, const int* in_sizes, int n_in,
                              void* d_out, int out_size, void* d_ws,
                              size_t ws_size, hipStream_t stream) {
  const float* x = (const float*)d_in[0];
  const float* w_qkv = (const float*)d_in[1];
  const float* temp = (const float*)d_in[2];
  const float* w_proj = (const float*)d_in[3];
  const float* gamma = (const float*)d_in[4];
  const float* beta = (const float*)d_in[5];
  float* out = (float*)d_out;
  char* w = (char*)d_ws;

  u16* wqkv_b = (u16*)(w);                 // 1.50 MB
  u16* wproj_b = (u16*)(w + 1572864);      // 0.50 MB
  u16* xrN = (u16*)(w + 2097152);          // 8.0 MB  [4096][1024]
  u16* qkvb = (u16*)(w + 10485760);        // 6.0 MB  [768][4096]
  u16* attN = (u16*)(w + 16777216);        // 2.0 MB  [4096][256]
  float* lowT = (float*)(w + 18874368);    // 16 MB   [1024][4096]
  float* kA = (float*)(w + 35651584);
  float* kB = (float*)(w + 35655680);

  // 1) weights -> bf16 (one launch)
  cvt2_k<<<1024, 256, 0, stream>>>(w_qkv, wqkv_b, 196608, w_proj, wproj_b,
                                   65536);
  // 2) pool -> xrN
  pool_k<<<16384, 256, 0, stream>>>(x, xrN);
  // 3) qkv GEMM: M=768,N=4096,K=1024
  mgemm_k<true><<<dim3(32, 6), 256, 0, stream>>>(wqkv_b, xrN, qkvb, 1024, 1024,
                                                 1024, 4096);
  // 4) fused attention -> attN
  attn_k<<<256, 256, 0, stream>>>(qkvb, temp, attN);
  // 5) proj GEMM at low res: M=1024,N=4096,K=256
  mgemm_k<false><<<dim3(32, 8), 256, 0, stream>>>(wproj_b, attN, lowT, 256, 256,
                                                  256, 4096);
  // 6) analytic BN stats
  stats_k<<<1024, 256, 0, stream>>>(lowT, gamma, beta, kA, kB);
  // 7) fused upsample + BN -> out
  up_bn_k<<<16384, 256, 0, stream>>>(lowT, kA, kB, out);
}